// Round 3
// baseline (333.722 us; speedup 1.0000x reference)
//
#include <hip/hip_runtime.h>
#include <math.h>
#include <stdint.h>

#define N 4096
#define S0 256
#define S1 128
#define S2 64
#define LDK 72    // LDS row stride in bf16 (144 B): conflict-free b128 frag reads
#define LDE 132   // LDS row stride in fp32 for staged epilogue tiles

typedef __bf16 bf16;
typedef __attribute__((ext_vector_type(8))) __bf16 bf16x8;
typedef __attribute__((ext_vector_type(4))) float f32x4;

// ---------------- fused chain: Wb = (U0@U1)@U2 in bf16 ----------------

__global__ __launch_bounds__(128) void k_chain1(const float* __restrict__ U0,
                                                const float* __restrict__ U1,
                                                const float* __restrict__ U2,
                                                bf16* __restrict__ Wb) {
    __shared__ float u0s[8][S0];
    __shared__ float ts[8][S1 + 4];
    int i0 = blockIdx.x * 8;
    int tid = threadIdx.x;
    for (int t = tid; t < 8 * S0; t += 128)
        u0s[t >> 8][t & 255] = U0[(i0 + (t >> 8)) * S0 + (t & 255)];
    __syncthreads();
    {
        int j = tid;
        float acc[8] = {};
        for (int k = 0; k < S0; ++k) {
            float u1 = U1[k * S1 + j];
#pragma unroll
            for (int r = 0; r < 8; ++r) acc[r] += u0s[r][k] * u1;
        }
        for (int r = 0; r < 8; ++r) ts[r][j] = acc[r];
    }
    __syncthreads();
    {
        int j = tid & 63, h = tid >> 6;  // h in {0,1}: rows h*4..h*4+3
        float acc2[4] = {};
        for (int k = 0; k < S1; ++k) {
            float u2 = U2[k * S2 + j];
#pragma unroll
            for (int r = 0; r < 4; ++r) acc2[r] += ts[h * 4 + r][k] * u2;
        }
        for (int r = 0; r < 4; ++r)
            Wb[(i0 + h * 4 + r) * S2 + j] = (bf16)acc2[r];
    }
}

// V2t = V2^T in bf16: (S2,N) -> (N,S2)
__global__ __launch_bounds__(256) void k_v2t(const float* __restrict__ V2,
                                             bf16* __restrict__ V2t) {
    __shared__ float t[64][65];
    int j0 = blockIdx.x * 64;
    for (int idx = threadIdx.x; idx < 4096; idx += 256) {
        int k = idx >> 6, c = idx & 63;
        t[c][k] = V2[k * N + j0 + c];
    }
    __syncthreads();
    for (int idx = threadIdx.x; idx < 4096; idx += 256) {
        int r = idx >> 6, k = idx & 63;
        V2t[(j0 + r) * 64 + k] = (bf16)t[r][k];
    }
}

// ---- fused chain: hn = l2norm_rows(elu(V2^T@fc1_w^T+fc1_b)@fc2_w^T+fc2_b) ----

__global__ __launch_bounds__(128) void k_chain2(const float* __restrict__ V2,
                                                const float* __restrict__ fc1_w,
                                                const float* __restrict__ fc1_b,
                                                const float* __restrict__ fc2_w,
                                                const float* __restrict__ fc2_b,
                                                bf16* __restrict__ hnb) {
    __shared__ float vs[8][S2];
    __shared__ float hs[8][S1 + 4];
    __shared__ float red[2][8];
    __shared__ float norms[8];
    int i0 = blockIdx.x * 8;
    int tid = threadIdx.x;
    for (int t = tid; t < 8 * S2; t += 128) {
        int r = t & 7, k = t >> 3;
        vs[r][k] = V2[k * N + i0 + r];
    }
    __syncthreads();
    {
        int j = tid;
        float b = fc1_b[j];
        float acc[8];
#pragma unroll
        for (int r = 0; r < 8; ++r) acc[r] = b;
        for (int k = 0; k < S2; ++k) {
            float w = fc1_w[j * S2 + k];
#pragma unroll
            for (int r = 0; r < 8; ++r) acc[r] += vs[r][k] * w;
        }
        for (int r = 0; r < 8; ++r) {
            float x = acc[r];
            hs[r][j] = x > 0.f ? x : (expf(x) - 1.f);
        }
    }
    __syncthreads();
    {
        int j = tid;
        float b0 = fc2_b[j], b1 = fc2_b[j + 128];
        float a0[8], a1[8];
#pragma unroll
        for (int r = 0; r < 8; ++r) { a0[r] = b0; a1[r] = b1; }
        for (int k = 0; k < S1; ++k) {
            float w0 = fc2_w[j * S1 + k];
            float w1 = fc2_w[(j + 128) * S1 + k];
#pragma unroll
            for (int r = 0; r < 8; ++r) { a0[r] += hs[r][k] * w0; a1[r] += hs[r][k] * w1; }
        }
        int lane = tid & 63, wv = tid >> 6;
#pragma unroll
        for (int r = 0; r < 8; ++r) {
            float v = a0[r] * a0[r] + a1[r] * a1[r];
            for (int off = 32; off; off >>= 1) v += __shfl_down(v, off, 64);
            if (lane == 0) red[wv][r] = v;
        }
        __syncthreads();
        if (tid < 8) norms[tid] = fmaxf(sqrtf(red[0][tid] + red[1][tid]), 1e-12f);
        __syncthreads();
        for (int r = 0; r < 8; ++r) {
            float inv = 1.f / norms[r];
            hnb[(i0 + r) * S0 + j] = (bf16)(a0[r] * inv);
            hnb[(i0 + r) * S0 + j + 128] = (bf16)(a1[r] * inv);
        }
    }
}

// ------- loss1: sum((A - Wb@V2t^T)^2), 128x128 MFMA tiles, staged-A epilogue -------

__global__ __launch_bounds__(256) void k_loss1(const bf16* __restrict__ Wb,
                                               const bf16* __restrict__ V2t,
                                               const float* __restrict__ A,
                                               double* __restrict__ acc) {
    __shared__ __align__(16) char smem[2 * 128 * LDK * 2];   // 36864 B
    bf16* As = (bf16*)smem;
    bf16* Bs = As + 128 * LDK;
    float* Ash = (float*)smem;       // reused for A-tile (64*LDE*4 = 33792 B)
    __shared__ double redd[4];
    int tid = threadIdx.x;
    int lane = tid & 63, w = tid >> 6;
    int i0 = blockIdx.y * 128, j0 = blockIdx.x * 128;
    int wm = (w >> 1) * 64, wn = (w & 1) * 64;

    f32x4 zero = {0.f, 0.f, 0.f, 0.f};
    f32x4 d[4][4];
#pragma unroll
    for (int a = 0; a < 4; ++a)
#pragma unroll
        for (int b = 0; b < 4; ++b) d[a][b] = zero;

#pragma unroll
    for (int t = 0; t < 4; ++t) {
        int idx = tid + 256 * t;
        int r = idx >> 3, c = idx & 7;
        uint4 va = *(const uint4*)(Wb + (i0 + r) * S2 + c * 8);
        uint4 vb = *(const uint4*)(V2t + (j0 + r) * S2 + c * 8);
        *(uint4*)(As + r * LDK + c * 8) = va;
        *(uint4*)(Bs + r * LDK + c * 8) = vb;
    }
    __syncthreads();
    int q = lane >> 4, l15 = lane & 15;
#pragma unroll
    for (int kk = 0; kk < 64; kk += 32) {
        bf16x8 af[4], bfr[4];
#pragma unroll
        for (int ta = 0; ta < 4; ++ta)
            af[ta] = *(const bf16x8*)(As + (wm + ta * 16 + l15) * LDK + kk + q * 8);
#pragma unroll
        for (int tb = 0; tb < 4; ++tb)
            bfr[tb] = *(const bf16x8*)(Bs + (wn + tb * 16 + l15) * LDK + kk + q * 8);
#pragma unroll
        for (int ta = 0; ta < 4; ++ta)
#pragma unroll
            for (int tb = 0; tb < 4; ++tb)
                d[ta][tb] = __builtin_amdgcn_mfma_f32_16x16x32_bf16(af[ta], bfr[tb], d[ta][tb], 0, 0, 0);
    }
    // epilogue: stage A tile in two 64-row chunks, coalesced float4
    float local = 0.f;
    for (int ch = 0; ch < 2; ++ch) {
        __syncthreads();
        for (int idx = tid; idx < 2048; idx += 256) {
            int r = idx >> 5, c4 = idx & 31;
            *(float4*)&Ash[r * LDE + c4 * 4] =
                *(const float4*)&A[(i0 + ch * 64 + r) * N + j0 + c4 * 4];
        }
        __syncthreads();
        if (wm == ch * 64) {
#pragma unroll
            for (int ta = 0; ta < 4; ++ta)
#pragma unroll
                for (int v = 0; v < 4; ++v) {
                    int row = ta * 16 + q * 4 + v;
#pragma unroll
                    for (int tb = 0; tb < 4; ++tb) {
                        float e = Ash[row * LDE + wn + tb * 16 + l15] - d[ta][tb][v];
                        local += e * e;
                    }
                }
        }
    }
    double dl = (double)local;
    for (int off = 32; off; off >>= 1) dl += __shfl_down(dl, off, 64);
    if (lane == 0) redd[w] = dl;
    __syncthreads();
    if (tid == 0) atomicAdd(acc, redd[0] + redd[1] + redd[2] + redd[3]);
}

// ------- fused refl_sim: rowsum + sim-mask pos, staged-sim epilogue -------

__global__ __launch_bounds__(256) void k_sim(const bf16* __restrict__ hnb,
                                             const float* __restrict__ sim,
                                             float* __restrict__ rowsum,
                                             float* __restrict__ pos4) {
    __shared__ __align__(16) char smem[2 * 128 * LDK * 2];
    bf16* As = (bf16*)smem;
    bf16* Bs = As + 128 * LDK;
    float* Ssh = (float*)smem;
    __shared__ float rs_l[128], ps_l[128];
    int tid = threadIdx.x;
    int lane = tid & 63, w = tid >> 6;
    int i0 = blockIdx.y * 128, j0 = blockIdx.x * 128;
    int wm = (w >> 1) * 64, wn = (w & 1) * 64;
    if (tid < 128) { rs_l[tid] = 0.f; ps_l[tid] = 0.f; }

    f32x4 zero = {0.f, 0.f, 0.f, 0.f};
    f32x4 d[4][4];
#pragma unroll
    for (int a = 0; a < 4; ++a)
#pragma unroll
        for (int b = 0; b < 4; ++b) d[a][b] = zero;

    int q = lane >> 4, l15 = lane & 15;
    for (int k0 = 0; k0 < S0; k0 += 64) {
        __syncthreads();
#pragma unroll
        for (int t = 0; t < 4; ++t) {
            int idx = tid + 256 * t;
            int r = idx >> 3, c = idx & 7;
            uint4 va = *(const uint4*)(hnb + (i0 + r) * S0 + k0 + c * 8);
            uint4 vb = *(const uint4*)(hnb + (j0 + r) * S0 + k0 + c * 8);
            *(uint4*)(As + r * LDK + c * 8) = va;
            *(uint4*)(Bs + r * LDK + c * 8) = vb;
        }
        __syncthreads();
#pragma unroll
        for (int kk = 0; kk < 64; kk += 32) {
            bf16x8 af[4], bfr[4];
#pragma unroll
            for (int ta = 0; ta < 4; ++ta)
                af[ta] = *(const bf16x8*)(As + (wm + ta * 16 + l15) * LDK + kk + q * 8);
#pragma unroll
            for (int tb = 0; tb < 4; ++tb)
                bfr[tb] = *(const bf16x8*)(Bs + (wn + tb * 16 + l15) * LDK + kk + q * 8);
#pragma unroll
            for (int ta = 0; ta < 4; ++ta)
#pragma unroll
                for (int tb = 0; tb < 4; ++tb)
                    d[ta][tb] = __builtin_amdgcn_mfma_f32_16x16x32_bf16(af[ta], bfr[tb], d[ta][tb], 0, 0, 0);
        }
    }
    // epilogue: stage sim tile in two 64-row chunks; s = exp(2*dot)
    for (int ch = 0; ch < 2; ++ch) {
        __syncthreads();
        for (int idx = tid; idx < 2048; idx += 256) {
            int r = idx >> 5, c4 = idx & 31;
            *(float4*)&Ssh[r * LDE + c4 * 4] =
                *(const float4*)&sim[(i0 + ch * 64 + r) * N + j0 + c4 * 4];
        }
        __syncthreads();
        if (wm == ch * 64) {
#pragma unroll
            for (int ta = 0; ta < 4; ++ta)
#pragma unroll
                for (int v = 0; v < 4; ++v) {
                    int row = ta * 16 + q * 4 + v;
                    float rs = 0.f, ps = 0.f;
#pragma unroll
                    for (int tb = 0; tb < 4; ++tb) {
                        float s = __expf(2.f * d[ta][tb][v]);
                        rs += s;
                        ps += (Ssh[row * LDE + wn + tb * 16 + l15] > 0.9f) ? s : 0.f;
                    }
#pragma unroll
                    for (int m = 1; m < 16; m <<= 1) {
                        rs += __shfl_xor(rs, m, 16);
                        ps += __shfl_xor(ps, m, 16);
                    }
                    if (l15 == 0) {
                        atomicAdd(&rs_l[wm + row], rs);
                        atomicAdd(&ps_l[wm + row], ps);
                    }
                }
        }
    }
    __syncthreads();
    if (tid < 128) {
        atomicAdd(&rowsum[i0 + tid], rs_l[tid]);
        atomicAdd(&pos4[i0 + tid], ps_l[tid]);
    }
}

// ------- clique/neighbor pos sums: one thread per (row, slot), deduped -------

__global__ __launch_bounds__(256) void k_pos_idx(const bf16* __restrict__ hnb,
                                                 const int* __restrict__ cIdx,
                                                 const int* __restrict__ nIdx,
                                                 float* __restrict__ pos2,
                                                 float* __restrict__ pos3) {
    int g = blockIdx.x * blockDim.x + threadIdx.x;
    if (g >= N * 24) return;
    int i = g / 24, s = g % 24;
    const int* idx;
    int kk;
    float* dst;
    if (s < 8) { idx = cIdx + i * 8; kk = s; dst = pos2; }
    else       { idx = nIdx + i * 16; kk = s - 8; dst = pos3; }
    int t = idx[kk];
    for (int k = 0; k < kk; ++k)
        if (idx[k] == t) return;  // mask is a set: duplicates count once
    const bf16* a = hnb + i * S0;
    const bf16* b = hnb + t * S0;
    float dsum = 0.f;
    for (int k = 0; k < S0; k += 8) {
        bf16x8 av = *(const bf16x8*)(a + k);
        bf16x8 bv = *(const bf16x8*)(b + k);
#pragma unroll
        for (int u = 0; u < 8; ++u) dsum += (float)av[u] * (float)bv[u];
    }
    atomicAdd(dst + i, __expf(2.f * dsum));
}

// ---------------- loss5: nonnegativity penalty ----------------

__global__ __launch_bounds__(256) void k_loss5(const float* __restrict__ U0,
                                               const float* __restrict__ U1,
                                               const float* __restrict__ U2,
                                               const float* __restrict__ V2,
                                               double* __restrict__ acc) {
    const int n0 = N * S0, n1 = S0 * S1, n2 = S1 * S2, n3 = S2 * N;
    const int total = n0 + n1 + n2 + n3;
    float local = 0.f;
    for (int t = blockIdx.x * blockDim.x + threadIdx.x; t < total;
         t += gridDim.x * blockDim.x) {
        int u = t;
        float x;
        if (u < n0) x = U0[u];
        else { u -= n0;
            if (u < n1) x = U1[u];
            else { u -= n1;
                if (u < n2) x = U2[u];
                else { u -= n2; x = V2[u]; }
            }
        }
        if (x < 0.f) local += x * x;
    }
    for (int off = 32; off; off >>= 1) local += __shfl_down(local, off, 64);
    if ((threadIdx.x & 63) == 0 && local != 0.f) atomicAdd(acc, (double)local);
}

// ---------------- finalize ----------------

__global__ __launch_bounds__(256) void k_final(const float* __restrict__ rowsum,
                                               const float* __restrict__ pos2,
                                               const float* __restrict__ pos3,
                                               const float* __restrict__ pos4,
                                               const double* __restrict__ lacc,
                                               float* __restrict__ out) {
    __shared__ double red[3][4];
    int tid = threadIdx.x;
    double l2 = 0, l3 = 0, l4 = 0;
    for (int i = tid; i < N; i += 256) {
        double rs = (double)rowsum[i];
        float p2 = pos2[i], p3 = pos3[i], p4 = pos4[i];
        if (p2 > 0.f) l2 -= log((double)p2 / rs);
        if (p3 > 0.f) l3 -= log((double)p3 / rs);
        if (p4 > 0.f) l4 -= log((double)p4 / rs);
    }
    int lane = tid & 63, wave = tid >> 6;
    for (int off = 32; off; off >>= 1) {
        l2 += __shfl_down(l2, off, 64);
        l3 += __shfl_down(l3, off, 64);
        l4 += __shfl_down(l4, off, 64);
    }
    if (lane == 0) { red[0][wave] = l2; red[1][wave] = l3; red[2][wave] = l4; }
    __syncthreads();
    if (tid == 0) {
        double L2 = 0, L3 = 0, L4 = 0;
        for (int w = 0; w < 4; ++w) { L2 += red[0][w]; L3 += red[1][w]; L4 += red[2][w]; }
        L2 /= N; L3 /= N; L4 /= N;
        double L1 = lacc[0], L5 = lacc[1];
        double total = L1 + 0.1 * (L2 + L3 + L4) + L5;
        out[0] = (float)total;
        out[1] = (float)L1;
        out[2] = (float)L2;
        out[3] = (float)L3;
        out[4] = (float)L4;
        out[5] = (float)L5;
    }
}

extern "C" void kernel_launch(void* const* d_in, const int* in_sizes, int n_in,
                              void* d_out, int out_size, void* d_ws, size_t ws_size,
                              hipStream_t stream) {
    const float* A     = (const float*)d_in[0];
    const float* U0    = (const float*)d_in[1];
    const float* U1    = (const float*)d_in[2];
    const float* U2    = (const float*)d_in[3];
    const float* V2    = (const float*)d_in[4];
    const float* fc1_w = (const float*)d_in[5];
    const float* fc1_b = (const float*)d_in[6];
    const float* fc2_w = (const float*)d_in[7];
    const float* fc2_b = (const float*)d_in[8];
    const float* sim   = (const float*)d_in[9];
    const int* cIdx    = (const int*)d_in[10];
    const int* nIdx    = (const int*)d_in[11];

    float* ws = (float*)d_ws;
    float* rowsum = ws;
    float* pos2 = ws + N;
    float* pos3 = ws + 2 * N;
    float* pos4 = ws + 3 * N;
    double* lacc = (double*)(ws + 4 * N);          // 2 doubles (loss1, loss5)
    bf16* hnb = (bf16*)(ws + 4 * N + 4);           // N*S0 bf16 (16B-aligned)
    bf16* Wb  = hnb + N * S0;                      // N*S2 bf16
    bf16* V2t = Wb + N * S2;                       // N*S2 bf16

    hipMemsetAsync(ws, 0, (4 * N + 4) * sizeof(float), stream);

    k_chain1<<<N / 8, 128, 0, stream>>>(U0, U1, U2, Wb);
    k_v2t<<<N / 64, 256, 0, stream>>>(V2, V2t);
    k_chain2<<<N / 8, 128, 0, stream>>>(V2, fc1_w, fc1_b, fc2_w, fc2_b, hnb);
    k_loss1<<<dim3(N / 128, N / 128), 256, 0, stream>>>(Wb, V2t, A, lacc);
    k_sim<<<dim3(N / 128, N / 128), 256, 0, stream>>>(hnb, sim, rowsum, pos4);
    k_pos_idx<<<(N * 24) / 256, 256, 0, stream>>>(hnb, cIdx, nIdx, pos2, pos3);
    k_loss5<<<1024, 256, 0, stream>>>(U0, U1, U2, V2, lacc + 1);
    k_final<<<1, 256, 0, stream>>>(rowsum, pos2, pos3, pos4, lacc, (float*)d_out);
}